// Round 8
// baseline (1905.320 us; speedup 1.0000x reference)
//
#include <hip/hip_runtime.h>

#define NV   50000
#define NR   5
#define NT   8
#define CIN  64
#define COUT 64
#define VPB  4
#define BARY (NR*NT*3)      // 120
#define KSTEP 32
#define NICC 10             // (NR*CIN)/KSTEP = 320/32 ic-chunks per j
#define BK_ELEMS (NR*CIN*NT*COUT)   // 320*512 = 163840 per array
#define BM2  64
#define NBLK2 ((NV + BM2 - 1) / BM2)   // 782

#define WL_BYTES 262144
#define WS_NEED  (WL_BYTES + 2u * BK_ELEMS * 2u)   // ~917 KB

typedef __bf16 bf16x8 __attribute__((ext_vector_type(8)));
typedef float  f32x4  __attribute__((ext_vector_type(4)));
typedef unsigned short ushort4v __attribute__((ext_vector_type(4)));

// ---------- K0: kernel -> bf16 hi/lo, [icc][m*64+d][rk] (un-rotated, 2x327 KB,
// L2-resident; rotation handled by per-wave column offset) ----------
__global__ __launch_bounds__(256) void build_bk(
    const float* __restrict__ kern, unsigned short* __restrict__ bkh,
    unsigned short* __restrict__ bkl)
{
    int e   = blockIdx.x * 256 + threadIdx.x;   // ((icc*512)+(m*64+d))*32+rk
    int rk  = e & 31;
    int md  = (e >> 5) & 511;
    int icc = e >> 14;
    int r   = icc * KSTEP + rk;                 // (i,c) flat
    int i   = r >> 6;
    int c   = r & 63;
    int m   = md >> 6;
    int d   = md & 63;
    float kv = kern[((i * NT + m) * CIN + c) * COUT + d];
    __bf16 h = (__bf16)kv;
    float hf = (float)h;
    __bf16 lo = (__bf16)(kv - hf);
    bkh[e] = __builtin_bit_cast(unsigned short, h);
    bkl[e] = __builtin_bit_cast(unsigned short, lo);
}

// ---------- main v4: un-rotated L2 B, NO B reg-dbuf, (512,4) occupancy ----------
__global__ __launch_bounds__(512, 4) void geo_mfma4(
    const float* __restrict__ signal,
    const float* __restrict__ bary_w,
    const int*   __restrict__ bary_idx,
    const unsigned short* __restrict__ bkh,
    const unsigned short* __restrict__ bkl,
    float* __restrict__ out,
    int*   __restrict__ wl)
{
    __shared__ __align__(16) unsigned short Ah[2][4][BM2][8];   // 8 KB
    __shared__ __align__(16) unsigned short Al[2][4][BM2][8];   // 8 KB
    __shared__ float nrm[BM2][NT];                              // 2 KB
    __shared__ int   besti[BM2];

    const int tid  = threadIdx.x;
    const int lane = tid & 63;
    const int wn   = tid >> 6;         // wave wn owns rotation k=wn
    const int g    = lane >> 4;
    const int l15  = lane & 15;
    const int vbase = blockIdx.x * BM2;

    // staging mapping: 512 threads = 64 vertices x 8 ch-quads (4 ch each)
    const int vt  = tid >> 3;
    const int cq  = tid & 7;
    const int oct = cq >> 1;
    const int pos = (cq & 1) * 4;

    f32x4 acc[4][4];
    {
        f32x4 z = {0.f, 0.f, 0.f, 0.f};
        #pragma unroll
        for (int mf = 0; mf < 4; ++mf)
            #pragma unroll
            for (int nf = 0; nf < 4; ++nf) acc[mf][nf] = z;
    }

    // ---- stage-load registers (issue-early, write-late: T14) ----
    float4 sp, sq, sr;
    float  sw0, sw1, sw2;
    bool   sv_ok = false;

    auto SLOAD = [&](int j, int icc) {
        const int i  = icc >> 1;
        const int c0 = (icc & 1) * 32;
        const int v  = vbase + vt;
        sv_ok = (v < NV);
        if (sv_ok) {
            const int base = v * BARY + (i * NT + j) * 3;
            sw0 = bary_w[base + 0];
            sw1 = bary_w[base + 1];
            sw2 = bary_w[base + 2];
            const int i0 = bary_idx[base + 0];
            const int i1 = bary_idx[base + 1];
            const int i2 = bary_idx[base + 2];
            const int ch = c0 + cq * 4;
            sp = *(const float4*)(signal + i0 * CIN + ch);
            sq = *(const float4*)(signal + i1 * CIN + ch);
            sr = *(const float4*)(signal + i2 * CIN + ch);
        }
    };
    auto SWRITE = [&](int b) {
        float xv[4];
        if (sv_ok) {
            xv[0] = sw0 * sp.x + sw1 * sq.x + sw2 * sr.x;
            xv[1] = sw0 * sp.y + sw1 * sq.y + sw2 * sr.y;
            xv[2] = sw0 * sp.z + sw1 * sq.z + sw2 * sr.z;
            xv[3] = sw0 * sp.w + sw1 * sq.w + sw2 * sr.w;
        } else {
            xv[0] = xv[1] = xv[2] = xv[3] = 0.f;
        }
        ushort4v hv, lv;
        #pragma unroll
        for (int e = 0; e < 4; ++e) {
            __bf16 h  = (__bf16)xv[e];
            float  hf = (float)h;
            __bf16 lo = (__bf16)(xv[e] - hf);
            hv[e] = __builtin_bit_cast(unsigned short, h);
            lv[e] = __builtin_bit_cast(unsigned short, lo);
        }
        *(ushort4v*)&Ah[b][oct][vt][pos] = hv;
        *(ushort4v*)&Al[b][oct][vt][pos] = lv;
    };

    // ---- prologue: stage it=0 into buf0 ----
    SLOAD(0, 0);
    SWRITE(0);
    __syncthreads();

    int it = 0;
    for (int j = 0; j < NT; ++j) {
        const int m = (j + wn) & 7;            // this wave's B column block
        for (int icc = 0; icc < NICC; ++icc, ++it) {
            const int b = it & 1;

            // B fragments for CURRENT chunk: issue first (L2-hit ~200-400 cyc,
            // in flight under the A ds_reads / next-stage loads)
            bf16x8 bh[4], bl[4];
            #pragma unroll
            for (int nf = 0; nf < 4; ++nf) {
                const int col  = m * 64 + nf * 16 + l15;
                const int base = (icc * 512 + col) * KSTEP + g * 8;
                bh[nf] = *(const bf16x8*)(bkh + base);
                bl[nf] = *(const bf16x8*)(bkl + base);
            }

            // A fragments (written by previous iteration)
            bf16x8 ah[4], al[4];
            #pragma unroll
            for (int mf = 0; mf < 4; ++mf) {
                ah[mf] = *(const bf16x8*)&Ah[b][g][mf * 16 + l15][0];
                al[mf] = *(const bf16x8*)&Al[b][g][mf * 16 + l15][0];
            }

            // issue next-chunk stage loads EARLY (hidden under MFMA)
            const int  iccn = (icc == NICC - 1) ? 0 : icc + 1;
            const int  jn   = (icc == NICC - 1) ? j + 1 : j;
            const bool have_next = (jn < NT);
            if (have_next) SLOAD(jn, iccn);

            // 48 MFMAs
            #pragma unroll
            for (int nf = 0; nf < 4; ++nf) {
                #pragma unroll
                for (int mf = 0; mf < 4; ++mf) {
                    acc[mf][nf] = __builtin_amdgcn_mfma_f32_16x16x32_bf16(ah[mf], bh[nf], acc[mf][nf], 0, 0, 0);
                    acc[mf][nf] = __builtin_amdgcn_mfma_f32_16x16x32_bf16(ah[mf], bl[nf], acc[mf][nf], 0, 0, 0);
                    acc[mf][nf] = __builtin_amdgcn_mfma_f32_16x16x32_bf16(al[mf], bh[nf], acc[mf][nf], 0, 0, 0);
                }
            }

            if (have_next) SWRITE(b ^ 1);      // convert + LDS write
            __syncthreads();
        }
    }

    // ---- epilogue: wave wn owns rotation wn; norms per row ----
    #pragma unroll
    for (int mf = 0; mf < 4; ++mf)
        #pragma unroll
        for (int ri = 0; ri < 4; ++ri) {
            float s = 0.f;
            #pragma unroll
            for (int nf = 0; nf < 4; ++nf) {
                float vv = acc[mf][nf][ri];
                s = fmaf(vv, vv, s);
            }
            #pragma unroll
            for (int off = 1; off < 16; off <<= 1)
                s += __shfl_xor(s, off);
            if (l15 == 0) nrm[mf * 16 + g * 4 + ri][wn] = s;
        }
    __syncthreads();

    if (tid < BM2) {
        const int v = vbase + tid;
        float bn = nrm[tid][0];
        float sec = -1e30f;
        int best = 0;
        #pragma unroll
        for (int k = 1; k < NT; ++k) {
            float nv = nrm[tid][k];
            if (nv > bn)       { sec = bn; bn = nv; best = k; }
            else if (nv > sec) { sec = nv; }
        }
        const bool flag = (bn - sec) <= (2e-3f + 4e-5f * bn);
        besti[tid] = flag ? -1 : best;
        if (flag && v < NV) { int p = atomicAdd(wl, 1); wl[1 + p] = v; }
    }
    __syncthreads();

    #pragma unroll
    for (int mf = 0; mf < 4; ++mf)
        #pragma unroll
        for (int ri = 0; ri < 4; ++ri) {
            const int row = mf * 16 + g * 4 + ri;
            const int v   = vbase + row;
            const int bsel = (v < NV) ? besti[row] : -1;
            if (bsel == wn) {
                #pragma unroll
                for (int nf = 0; nf < 4; ++nf) {
                    const int d = nf * 16 + l15;
                    out[v * COUT + d] = fmaxf(acc[mf][nf][ri], 0.0f);
                }
            }
        }
}

// ---------- parallel fp64 refine: one BLOCK (4 waves) per vertex ----------
// K=320 split across 4 waves; fixed-order partial reduction (deterministic).
__global__ __launch_bounds__(256) void geo_refine_f64p(
    const float* __restrict__ signal,
    const float* __restrict__ bary_w,
    const int*   __restrict__ bary_idx,
    const float* __restrict__ kern,
    float*       __restrict__ out,
    const int*   __restrict__ wl,
    int nall)
{
    __shared__ __align__(16) float xs[NR][CIN][NT];   // 10 KB
    __shared__ double part[4][NT][COUT];              // 16 KB
    __shared__ double convl[NT][COUT];                // 4 KB
    __shared__ double nks[NT];
    __shared__ int bestS;

    const int tid  = threadIdx.x;
    const int wave = tid >> 6;
    const int lane = tid & 63;
    const int count = wl ? wl[0] : nall;

    for (int w = blockIdx.x; w < count; w += gridDim.x) {
        const int v = wl ? wl[1 + w] : w;

        // stage pullback x[i,c,j]; waves split the 40 (i,j) pairs
        for (int ij = wave; ij < NR * NT; ij += 4) {
            const int i = ij >> 3, j = ij & 7;
            const int base = v * BARY + ij * 3;
            const float w0 = bary_w[base], w1 = bary_w[base+1], w2 = bary_w[base+2];
            const int   i0 = bary_idx[base], i1 = bary_idx[base+1], i2 = bary_idx[base+2];
            xs[i][lane][j] = w0 * signal[i0*CIN + lane]
                           + w1 * signal[i1*CIN + lane]
                           + w2 * signal[i2*CIN + lane];
        }
        __syncthreads();

        double acc[NT];
        #pragma unroll
        for (int k = 0; k < NT; ++k) acc[k] = 0.0;

        for (int r = wave * 80; r < wave * 80 + 80; ++r) {
            const int i = r >> 6, c = r & 63;
            const float4 xa = *reinterpret_cast<const float4*>(&xs[i][c][0]);
            const float4 xb = *reinterpret_cast<const float4*>(&xs[i][c][4]);
            const double x8[NT] = {(double)xa.x, (double)xa.y, (double)xa.z, (double)xa.w,
                                   (double)xb.x, (double)xb.y, (double)xb.z, (double)xb.w};
            #pragma unroll
            for (int mm = 0; mm < NT; ++mm) {
                const double kv = (double)kern[((i * NT + mm) * CIN + c) * COUT + lane];
                #pragma unroll
                for (int k = 0; k < NT; ++k)
                    acc[k] = fma(x8[(mm - k + NT) & (NT - 1)], kv, acc[k]);
            }
        }
        #pragma unroll
        for (int k = 0; k < NT; ++k) part[wave][k][lane] = acc[k];
        __syncthreads();

        for (int kd = tid; kd < NT * COUT; kd += 256) {
            const int k = kd >> 6, d = kd & 63;
            convl[k][d] = ((part[0][k][d] + part[1][k][d])
                         + (part[2][k][d] + part[3][k][d]));
        }
        __syncthreads();

        for (int k = wave; k < NT; k += 4) {
            double n = convl[k][lane] * convl[k][lane];
            #pragma unroll
            for (int off = 32; off >= 1; off >>= 1) n += __shfl_xor(n, off);
            if (lane == 0) nks[k] = n;
        }
        __syncthreads();

        if (tid == 0) {
            int best = 0; double bn = nks[0];
            #pragma unroll
            for (int k = 1; k < NT; ++k)
                if (nks[k] > bn) { bn = nks[k]; best = k; }
            bestS = best;
        }
        __syncthreads();

        if (tid < COUT) out[v * COUT + tid] = fmaxf((float)convl[bestS][tid], 0.0f);
        __syncthreads();   // xs reused next iteration
    }
}

// ---------- round-3 fp32 two-pass fallback (ws too small for Bk) ----------
__global__ __launch_bounds__(256) void geo_conv_f32(
    const float* __restrict__ signal,
    const float* __restrict__ bary_w,
    const int*   __restrict__ bary_idx,
    const float* __restrict__ kern,
    float*       __restrict__ out,
    int*         __restrict__ wl)
{
    __shared__ __align__(16) float xs[VPB][NR][CIN][NT];
    __shared__ float wsh[VPB][BARY];
    __shared__ int   ish[VPB][BARY];

    const int tid   = threadIdx.x;
    const int wave  = tid >> 6;
    const int lane  = tid & 63;
    const int vbase = blockIdx.x * VPB;

    for (int e = tid; e < VPB * BARY; e += 256) {
        int s = e / BARY, r = e - s * BARY;
        wsh[s][r] = bary_w[(vbase + s) * BARY + r];
        ish[s][r] = bary_idx[(vbase + s) * BARY + r];
    }
    __syncthreads();
    {
        const int s = wave;
        for (int ij = 0; ij < NR * NT; ++ij) {
            int i = ij >> 3, j = ij & 7;
            float w0 = wsh[s][ij*3], w1 = wsh[s][ij*3+1], w2 = wsh[s][ij*3+2];
            int   i0 = ish[s][ij*3], i1 = ish[s][ij*3+1], i2 = ish[s][ij*3+2];
            xs[s][i][lane][j] = w0 * signal[i0*CIN + lane]
                              + w1 * signal[i1*CIN + lane]
                              + w2 * signal[i2*CIN + lane];
        }
    }
    __syncthreads();

    float acc[NT];
    #pragma unroll
    for (int k = 0; k < NT; ++k) acc[k] = 0.0f;
    const int s = wave, d = lane;
    for (int i = 0; i < NR; ++i) {
        const float* __restrict__ Ki = kern + i * (NT * CIN * COUT);
        for (int c = 0; c < CIN; ++c) {
            float4 xa = *reinterpret_cast<const float4*>(&xs[s][i][c][0]);
            float4 xb = *reinterpret_cast<const float4*>(&xs[s][i][c][4]);
            float x8[NT] = {xa.x, xa.y, xa.z, xa.w, xb.x, xb.y, xb.z, xb.w};
            #pragma unroll
            for (int mm = 0; mm < NT; ++mm) {
                float kv = Ki[(mm * CIN + c) * COUT + d];
                #pragma unroll
                for (int k = 0; k < NT; ++k)
                    acc[k] = fmaf(x8[(mm - k + NT) & (NT - 1)], kv, acc[k]);
            }
        }
    }
    double nk[NT];
    #pragma unroll
    for (int k = 0; k < NT; ++k) {
        double n = (double)acc[k] * (double)acc[k];
        #pragma unroll
        for (int off = 32; off >= 1; off >>= 1) n += __shfl_xor(n, off);
        nk[k] = n;
    }
    int best = 0; double bn = nk[0], sec = -1.0e300;
    #pragma unroll
    for (int k = 1; k < NT; ++k) {
        if (nk[k] > bn)       { sec = bn; bn = nk[k]; best = k; }
        else if (nk[k] > sec) { sec = nk[k]; }
    }
    const int v = vbase + s;
    if (bn - sec <= 4.0e-3 + 3.0e-5 * bn) {
        if (lane == 0) { int pos = atomicAdd(wl, 1); wl[1 + pos] = v; }
    } else {
        float sel = acc[0];
        #pragma unroll
        for (int k = 1; k < NT; ++k) sel = (best == k) ? acc[k] : sel;
        out[v * COUT + d] = fmaxf(sel, 0.0f);
    }
}

extern "C" void kernel_launch(void* const* d_in, const int* in_sizes, int n_in,
                              void* d_out, int out_size, void* d_ws, size_t ws_size,
                              hipStream_t stream) {
    const float* signal   = (const float*)d_in[0];
    const float* bary_w   = (const float*)d_in[1];
    const int*   bary_idx = (const int*)d_in[2];
    const float* kern     = (const float*)d_in[3];
    float* out = (float*)d_out;

    if (ws_size >= (size_t)WS_NEED) {
        int* wl = (int*)d_ws;
        unsigned short* bkh = (unsigned short*)((char*)d_ws + WL_BYTES);
        unsigned short* bkl = bkh + BK_ELEMS;
        hipMemsetAsync(wl, 0, sizeof(int), stream);
        build_bk<<<dim3(BK_ELEMS / 256), dim3(256), 0, stream>>>(kern, bkh, bkl);
        geo_mfma4<<<dim3(NBLK2), dim3(512), 0, stream>>>(
            signal, bary_w, bary_idx, bkh, bkl, out, wl);
        geo_refine_f64p<<<dim3(512), dim3(256), 0, stream>>>(
            signal, bary_w, bary_idx, kern, out, wl, 0);
    } else if (ws_size >= (size_t)(1 + NV) * sizeof(int)) {
        int* wl = (int*)d_ws;
        hipMemsetAsync(wl, 0, sizeof(int), stream);
        geo_conv_f32<<<dim3(NV / VPB), dim3(256), 0, stream>>>(
            signal, bary_w, bary_idx, kern, out, wl);
        geo_refine_f64p<<<dim3(512), dim3(256), 0, stream>>>(
            signal, bary_w, bary_idx, kern, out, wl, 0);
    } else {
        geo_refine_f64p<<<dim3(1024), dim3(256), 0, stream>>>(
            signal, bary_w, bary_idx, kern, out, nullptr, NV);
    }
}

// Round 9
// 650.680 us; speedup vs baseline: 2.9282x; 2.9282x over previous
//
#include <hip/hip_runtime.h>

#define NV   50000
#define NR   5
#define NT   8
#define CIN  64
#define COUT 64
#define VPB  4
#define BARY (NR*NT*3)      // 120
#define BK_ELEMS (NR*CIN*NT*COUT)   // 163840 fp16 elems (327 KB) — L2-resident
#define BM2  64
#define NBLK2 ((NV + BM2 - 1) / BM2)   // 782
#define NCHUNK5 (NT*NR)     // 40 chunks of K=64 (one (j,i) pair each)

#define WL_BYTES 262144
#define WS_NEED  (WL_BYTES + 2u * BK_ELEMS)   // ~590 KB

typedef _Float16 f16x8 __attribute__((ext_vector_type(8)));
typedef float    f32x4 __attribute__((ext_vector_type(4)));
typedef _Float16 f16x8s __attribute__((ext_vector_type(8)));

// ---------- K0: kernel -> fp16, layout [i][m*64+d][c] (un-rotated; rotation
// handled by per-wave column offset; 327 KB total) ----------
__global__ __launch_bounds__(256) void build_bk5(
    const float* __restrict__ kern, _Float16* __restrict__ bk)
{
    int e  = blockIdx.x * 256 + threadIdx.x;   // ((i*512)+(m*64+d))*64 + c
    int c  = e & 63;
    int md = (e >> 6) & 511;
    int i  = e >> 15;
    int m  = md >> 6;
    int d  = md & 63;
    bk[e] = (_Float16)kern[((i * NT + m) * CIN + c) * COUT + d];
}

// ---------- main v5: single fp16 MFMA, KSTEP=64, L2 B, (512,4) ----------
__global__ __launch_bounds__(512, 4) void geo_mfma5(
    const float* __restrict__ signal,
    const float* __restrict__ bary_w,
    const int*   __restrict__ bary_idx,
    const _Float16* __restrict__ bk,
    float* __restrict__ out,
    int*   __restrict__ wl)
{
    // A tile: [buf][ch-octet][row][8 ch] fp16 = 16 KB total
    __shared__ __align__(16) _Float16 Axs[2][8][BM2][8];
    __shared__ float nrm[BM2][NT];
    __shared__ int   besti[BM2];

    const int tid  = threadIdx.x;
    const int lane = tid & 63;
    const int wn   = tid >> 6;         // wave wn owns rotation k=wn
    const int g    = lane >> 4;
    const int l15  = lane & 15;
    const int vbase = blockIdx.x * BM2;

    // staging mapping: wave-local. vt = w*8 + (l&7) (bank-friendly writes),
    // cq = l>>3 -> channels cq*8..+8. 512 threads = 64 v x 64 ch.
    const int vt = (tid >> 6) * 8 + (lane & 7);
    const int cq = lane >> 3;
    const int v_mine = vbase + vt;
    const bool v_ok = (v_mine < NV);

    f32x4 acc[4][4];
    {
        f32x4 z = {0.f, 0.f, 0.f, 0.f};
        #pragma unroll
        for (int mf = 0; mf < 4; ++mf)
            #pragma unroll
            for (int nf = 0; nf < 4; ++nf) acc[mf][nf] = z;
    }

    // bary regs for the NEXT chunk to stage (6 regs live across MFMA)
    float bw0, bw1, bw2;
    int   bi0, bi1, bi2;

    auto SLOADB = [&](int it2) {            // chunk it2 = j*NR + i
        const int j2 = it2 / NR;
        const int i2 = it2 - j2 * NR;
        if (v_ok) {
            const int base = v_mine * BARY + (i2 * NT + j2) * 3;
            bw0 = bary_w[base + 0];
            bw1 = bary_w[base + 1];
            bw2 = bary_w[base + 2];
            bi0 = bary_idx[base + 0];
            bi1 = bary_idx[base + 1];
            bi2 = bary_idx[base + 2];
        }
    };
    auto SWRITE = [&](int b) {              // signal gather + cvt + LDS write
        float xv[8];
        if (v_ok) {
            const int ch = cq * 8;
            const float4* s0 = (const float4*)(signal + bi0 * CIN + ch);
            const float4* s1 = (const float4*)(signal + bi1 * CIN + ch);
            const float4* s2 = (const float4*)(signal + bi2 * CIN + ch);
            const float4 p0 = s0[0], p1 = s0[1];
            const float4 q0 = s1[0], q1 = s1[1];
            const float4 r0 = s2[0], r1 = s2[1];
            xv[0] = bw0*p0.x + bw1*q0.x + bw2*r0.x;
            xv[1] = bw0*p0.y + bw1*q0.y + bw2*r0.y;
            xv[2] = bw0*p0.z + bw1*q0.z + bw2*r0.z;
            xv[3] = bw0*p0.w + bw1*q0.w + bw2*r0.w;
            xv[4] = bw0*p1.x + bw1*q1.x + bw2*r1.x;
            xv[5] = bw0*p1.y + bw1*q1.y + bw2*r1.y;
            xv[6] = bw0*p1.z + bw1*q1.z + bw2*r1.z;
            xv[7] = bw0*p1.w + bw1*q1.w + bw2*r1.w;
        } else {
            #pragma unroll
            for (int e = 0; e < 8; ++e) xv[e] = 0.f;
        }
        f16x8 hv;
        #pragma unroll
        for (int e = 0; e < 8; ++e) hv[e] = (_Float16)xv[e];
        *(f16x8*)&Axs[b][cq][vt][0] = hv;
    };

    // ---- prologue: stage chunk 0 into buf0; preload bary for chunk 1 ----
    SLOADB(0);
    SWRITE(0);
    SLOADB(1);
    __syncthreads();

    for (int it = 0; it < NCHUNK5; ++it) {
        const int b = it & 1;
        const int j = it / NR;
        const int i = it - j * NR;
        const int m = (j + wn) & 7;     // this wave's B column block

        #pragma unroll
        for (int kk = 0; kk < 2; ++kk) {
            // B fragments (L2-hit): col-major [i][col][c]
            f16x8 bfrag[4];
            #pragma unroll
            for (int nf = 0; nf < 4; ++nf) {
                const int col = m * 64 + nf * 16 + l15;
                bfrag[nf] = *(const f16x8*)(bk + ((i * 512 + col) << 6) + kk * 32 + g * 8);
            }
            // A fragments from LDS: ch-octet = kk*4+g
            f16x8 afrag[4];
            #pragma unroll
            for (int mf = 0; mf < 4; ++mf)
                afrag[mf] = *(const f16x8*)&Axs[b][kk * 4 + g][mf * 16 + l15][0];

            #pragma unroll
            for (int nf = 0; nf < 4; ++nf)
                #pragma unroll
                for (int mf = 0; mf < 4; ++mf)
                    acc[mf][nf] = __builtin_amdgcn_mfma_f32_16x16x32_f16(
                        afrag[mf], bfrag[nf], acc[mf][nf], 0, 0, 0);
        }

        if (it + 1 < NCHUNK5) {
            SWRITE(b ^ 1);                    // stage chunk it+1 (bary preloaded)
            if (it + 2 < NCHUNK5) SLOADB(it + 2);
        }
        __syncthreads();
    }

    // ---- epilogue: wave wn owns rotation wn; norms per row ----
    #pragma unroll
    for (int mf = 0; mf < 4; ++mf)
        #pragma unroll
        for (int ri = 0; ri < 4; ++ri) {
            float s = 0.f;
            #pragma unroll
            for (int nf = 0; nf < 4; ++nf) {
                float vv = acc[mf][nf][ri];
                s = fmaf(vv, vv, s);
            }
            #pragma unroll
            for (int off = 1; off < 16; off <<= 1)
                s += __shfl_xor(s, off);
            if (l15 == 0) nrm[mf * 16 + g * 4 + ri][wn] = s;
        }
    __syncthreads();

    if (tid < BM2) {
        const int v = vbase + tid;
        float bn = nrm[tid][0];
        float sec = -1e30f;
        int best = 0;
        #pragma unroll
        for (int k = 1; k < NT; ++k) {
            float nv = nrm[tid][k];
            if (nv > bn)       { sec = bn; bn = nv; best = k; }
            else if (nv > sec) { sec = nv; }
        }
        // fp16-input norm^2 error sigma ~9e-3; threshold ~6 sigma + rel term
        const bool flag = (bn - sec) <= (5.5e-2f + 1.5e-3f * bn);
        besti[tid] = flag ? -1 : best;
        if (flag && v < NV) { int p = atomicAdd(wl, 1); wl[1 + p] = v; }
    }
    __syncthreads();

    #pragma unroll
    for (int mf = 0; mf < 4; ++mf)
        #pragma unroll
        for (int ri = 0; ri < 4; ++ri) {
            const int row = mf * 16 + g * 4 + ri;
            const int v   = vbase + row;
            const int bsel = (v < NV) ? besti[row] : -1;
            if (bsel == wn) {
                #pragma unroll
                for (int nf = 0; nf < 4; ++nf) {
                    const int d = nf * 16 + l15;
                    out[v * COUT + d] = fmaxf(acc[mf][nf][ri], 0.0f);
                }
            }
        }
}

// ---------- parallel fp64 refine: one BLOCK (4 waves) per vertex ----------
__global__ __launch_bounds__(256) void geo_refine_f64p(
    const float* __restrict__ signal,
    const float* __restrict__ bary_w,
    const int*   __restrict__ bary_idx,
    const float* __restrict__ kern,
    float*       __restrict__ out,
    const int*   __restrict__ wl,
    int nall)
{
    __shared__ __align__(16) float xs[NR][CIN][NT];   // 10 KB
    __shared__ double part[4][NT][COUT];              // 16 KB
    __shared__ double convl[NT][COUT];                // 4 KB
    __shared__ double nks[NT];
    __shared__ int bestS;

    const int tid  = threadIdx.x;
    const int wave = tid >> 6;
    const int lane = tid & 63;
    const int count = wl ? wl[0] : nall;

    for (int w = blockIdx.x; w < count; w += gridDim.x) {
        const int v = wl ? wl[1 + w] : w;

        for (int ij = wave; ij < NR * NT; ij += 4) {
            const int i = ij >> 3, j = ij & 7;
            const int base = v * BARY + ij * 3;
            const float w0 = bary_w[base], w1 = bary_w[base+1], w2 = bary_w[base+2];
            const int   i0 = bary_idx[base], i1 = bary_idx[base+1], i2 = bary_idx[base+2];
            xs[i][lane][j] = w0 * signal[i0*CIN + lane]
                           + w1 * signal[i1*CIN + lane]
                           + w2 * signal[i2*CIN + lane];
        }
        __syncthreads();

        double acc[NT];
        #pragma unroll
        for (int k = 0; k < NT; ++k) acc[k] = 0.0;

        for (int r = wave * 80; r < wave * 80 + 80; ++r) {
            const int i = r >> 6, c = r & 63;
            const float4 xa = *reinterpret_cast<const float4*>(&xs[i][c][0]);
            const float4 xb = *reinterpret_cast<const float4*>(&xs[i][c][4]);
            const double x8[NT] = {(double)xa.x, (double)xa.y, (double)xa.z, (double)xa.w,
                                   (double)xb.x, (double)xb.y, (double)xb.z, (double)xb.w};
            #pragma unroll
            for (int mm = 0; mm < NT; ++mm) {
                const double kv = (double)kern[((i * NT + mm) * CIN + c) * COUT + lane];
                #pragma unroll
                for (int k = 0; k < NT; ++k)
                    acc[k] = fma(x8[(mm - k + NT) & (NT - 1)], kv, acc[k]);
            }
        }
        #pragma unroll
        for (int k = 0; k < NT; ++k) part[wave][k][lane] = acc[k];
        __syncthreads();

        for (int kd = tid; kd < NT * COUT; kd += 256) {
            const int k = kd >> 6, d = kd & 63;
            convl[k][d] = ((part[0][k][d] + part[1][k][d])
                         + (part[2][k][d] + part[3][k][d]));
        }
        __syncthreads();

        for (int k = wave; k < NT; k += 4) {
            double n = convl[k][lane] * convl[k][lane];
            #pragma unroll
            for (int off = 32; off >= 1; off >>= 1) n += __shfl_xor(n, off);
            if (lane == 0) nks[k] = n;
        }
        __syncthreads();

        if (tid == 0) {
            int best = 0; double bn = nks[0];
            #pragma unroll
            for (int k = 1; k < NT; ++k)
                if (nks[k] > bn) { bn = nks[k]; best = k; }
            bestS = best;
        }
        __syncthreads();

        if (tid < COUT) out[v * COUT + tid] = fmaxf((float)convl[bestS][tid], 0.0f);
        __syncthreads();
    }
}

// ---------- fp32 two-pass fallback (ws too small for bk) ----------
__global__ __launch_bounds__(256) void geo_conv_f32(
    const float* __restrict__ signal,
    const float* __restrict__ bary_w,
    const int*   __restrict__ bary_idx,
    const float* __restrict__ kern,
    float*       __restrict__ out,
    int*         __restrict__ wl)
{
    __shared__ __align__(16) float xs[VPB][NR][CIN][NT];
    __shared__ float wsh[VPB][BARY];
    __shared__ int   ish[VPB][BARY];

    const int tid   = threadIdx.x;
    const int wave  = tid >> 6;
    const int lane  = tid & 63;
    const int vbase = blockIdx.x * VPB;

    for (int e = tid; e < VPB * BARY; e += 256) {
        int s = e / BARY, r = e - s * BARY;
        wsh[s][r] = bary_w[(vbase + s) * BARY + r];
        ish[s][r] = bary_idx[(vbase + s) * BARY + r];
    }
    __syncthreads();
    {
        const int s = wave;
        for (int ij = 0; ij < NR * NT; ++ij) {
            int i = ij >> 3, j = ij & 7;
            float w0 = wsh[s][ij*3], w1 = wsh[s][ij*3+1], w2 = wsh[s][ij*3+2];
            int   i0 = ish[s][ij*3], i1 = ish[s][ij*3+1], i2 = ish[s][ij*3+2];
            xs[s][i][lane][j] = w0 * signal[i0*CIN + lane]
                              + w1 * signal[i1*CIN + lane]
                              + w2 * signal[i2*CIN + lane];
        }
    }
    __syncthreads();

    float acc[NT];
    #pragma unroll
    for (int k = 0; k < NT; ++k) acc[k] = 0.0f;
    const int s = wave, d = lane;
    for (int i = 0; i < NR; ++i) {
        const float* __restrict__ Ki = kern + i * (NT * CIN * COUT);
        for (int c = 0; c < CIN; ++c) {
            float4 xa = *reinterpret_cast<const float4*>(&xs[s][i][c][0]);
            float4 xb = *reinterpret_cast<const float4*>(&xs[s][i][c][4]);
            float x8[NT] = {xa.x, xa.y, xa.z, xa.w, xb.x, xb.y, xb.z, xb.w};
            #pragma unroll
            for (int mm = 0; mm < NT; ++mm) {
                float kv = Ki[(mm * CIN + c) * COUT + d];
                #pragma unroll
                for (int k = 0; k < NT; ++k)
                    acc[k] = fmaf(x8[(mm - k + NT) & (NT - 1)], kv, acc[k]);
            }
        }
    }
    double nk[NT];
    #pragma unroll
    for (int k = 0; k < NT; ++k) {
        double n = (double)acc[k] * (double)acc[k];
        #pragma unroll
        for (int off = 32; off >= 1; off >>= 1) n += __shfl_xor(n, off);
        nk[k] = n;
    }
    int best = 0; double bn = nk[0], sec = -1.0e300;
    #pragma unroll
    for (int k = 1; k < NT; ++k) {
        if (nk[k] > bn)       { sec = bn; bn = nk[k]; best = k; }
        else if (nk[k] > sec) { sec = nk[k]; }
    }
    const int v = vbase + s;
    if (bn - sec <= 4.0e-3 + 3.0e-5 * bn) {
        if (lane == 0) { int pos = atomicAdd(wl, 1); wl[1 + pos] = v; }
    } else {
        float sel = acc[0];
        #pragma unroll
        for (int k = 1; k < NT; ++k) sel = (best == k) ? acc[k] : sel;
        out[v * COUT + d] = fmaxf(sel, 0.0f);
    }
}

extern "C" void kernel_launch(void* const* d_in, const int* in_sizes, int n_in,
                              void* d_out, int out_size, void* d_ws, size_t ws_size,
                              hipStream_t stream) {
    const float* signal   = (const float*)d_in[0];
    const float* bary_w   = (const float*)d_in[1];
    const int*   bary_idx = (const int*)d_in[2];
    const float* kern     = (const float*)d_in[3];
    float* out = (float*)d_out;

    if (ws_size >= (size_t)WS_NEED) {
        int* wl = (int*)d_ws;
        _Float16* bk = (_Float16*)((char*)d_ws + WL_BYTES);
        hipMemsetAsync(wl, 0, sizeof(int), stream);
        build_bk5<<<dim3(BK_ELEMS / 256), dim3(256), 0, stream>>>(kern, bk);
        geo_mfma5<<<dim3(NBLK2), dim3(512), 0, stream>>>(
            signal, bary_w, bary_idx, bk, out, wl);
        geo_refine_f64p<<<dim3(1024), dim3(256), 0, stream>>>(
            signal, bary_w, bary_idx, kern, out, wl, 0);
    } else if (ws_size >= (size_t)(1 + NV) * sizeof(int)) {
        int* wl = (int*)d_ws;
        hipMemsetAsync(wl, 0, sizeof(int), stream);
        geo_conv_f32<<<dim3(NV / VPB), dim3(256), 0, stream>>>(
            signal, bary_w, bary_idx, kern, out, wl);
        geo_refine_f64p<<<dim3(512), dim3(256), 0, stream>>>(
            signal, bary_w, bary_idx, kern, out, wl, 0);
    } else {
        geo_refine_f64p<<<dim3(1024), dim3(256), 0, stream>>>(
            signal, bary_w, bary_idx, kern, out, nullptr, NV);
    }
}

// Round 10
// 508.762 us; speedup vs baseline: 3.7450x; 1.2789x over previous
//
#include <hip/hip_runtime.h>

#define NV   50000
#define NR   5
#define NT   8
#define CIN  64
#define COUT 64
#define BARY (NR*NT*3)      // 120
#define BK_ELEMS (NR*CIN*NT*COUT)   // 163840 fp16 elems (327 KB) — L2-resident
#define BM2  64
#define NBLK2 ((NV + BM2 - 1) / BM2)   // 782
#define NCHUNK5 (NT*NR)     // 40 chunks of K=64 (one (j,i) pair each)

#define WL_BYTES 262144
#define SIG16_BYTES (NV*CIN*2)                       // 6.4 MB
#define WS_NEED6 (WL_BYTES + 2u*BK_ELEMS + SIG16_BYTES)  // ~6.99 MB
#define WS_NEED5 (WL_BYTES + 2u*BK_ELEMS)                // ~590 KB

typedef _Float16 f16x8 __attribute__((ext_vector_type(8)));
typedef float    f32x4 __attribute__((ext_vector_type(4)));

// ---------- K0a: kernel -> fp16, layout [i][m*64+d][c] (un-rotated) ----------
__global__ __launch_bounds__(256) void build_bk5(
    const float* __restrict__ kern, _Float16* __restrict__ bk)
{
    int e  = blockIdx.x * 256 + threadIdx.x;   // ((i*512)+(m*64+d))*64 + c
    int c  = e & 63;
    int md = (e >> 6) & 511;
    int i  = e >> 15;
    int m  = md >> 6;
    int d  = md & 63;
    bk[e] = (_Float16)kern[((i * NT + m) * CIN + c) * COUT + d];
}

// ---------- K0b: signal -> fp16 (gathers then read 2B/elem not 4B) ----------
__global__ __launch_bounds__(256) void build_sig16(
    const float* __restrict__ signal, _Float16* __restrict__ sig16)
{
    int e = blockIdx.x * 256 + threadIdx.x;    // NV*CIN = 3.2e6 exact
    sig16[e] = (_Float16)signal[e];
}

// ---------- main v6: reg-pipelined gathers (3-deep), x-from-regs, fp16 MFMA ----------
__global__ __launch_bounds__(512, 4) void geo_mfma6(
    const float* __restrict__ bary_w,
    const int*   __restrict__ bary_idx,
    const _Float16* __restrict__ sig16,
    const _Float16* __restrict__ bk,
    float* __restrict__ out,
    int*   __restrict__ wl)
{
    // A tile single-buffer, padded: [row][9 slots of 8ch] -> 2-way max conflicts
    __shared__ __align__(16) _Float16 Axs[BM2 * 72];    // 9.2 KB
    __shared__ float nrm[BM2][NT];
    __shared__ int   besti[BM2];

    const int tid  = threadIdx.x;
    const int lane = tid & 63;
    const int wn   = tid >> 6;         // wave wn owns rotation k=wn
    const int g    = lane >> 4;
    const int l15  = lane & 15;
    const int vbase = blockIdx.x * BM2;

    // staging mapping: thread owns (vertex vt, channel octet cq)
    const int vt = tid >> 3;
    const int cq = tid & 7;
    const int v_mine = vbase + vt;
    const bool v_ok = (v_mine < NV);

    f32x4 acc[4][4];
    {
        f32x4 z = {0.f, 0.f, 0.f, 0.f};
        #pragma unroll
        for (int mf = 0; mf < 4; ++mf)
            #pragma unroll
            for (int nf = 0; nf < 4; ++nf) acc[mf][nf] = z;
    }

    struct Gen { float w0, w1, w2; int i0, i1, i2; };
    auto LOADGEN = [&](int it2) -> Gen {
        Gen gg;
        const int itc = (it2 < NCHUNK5) ? it2 : (NCHUNK5 - 1);
        const int j2 = itc / NR;
        const int i2 = itc - j2 * NR;
        if (v_ok) {
            const int base = v_mine * BARY + (i2 * NT + j2) * 3;
            gg.w0 = bary_w[base + 0];
            gg.w1 = bary_w[base + 1];
            gg.w2 = bary_w[base + 2];
            gg.i0 = bary_idx[base + 0];
            gg.i1 = bary_idx[base + 1];
            gg.i2 = bary_idx[base + 2];
        } else {
            gg.w0 = gg.w1 = gg.w2 = 0.f;
            gg.i0 = gg.i1 = gg.i2 = 0;    // safe address, weight 0
        }
        return gg;
    };

    f16x8 sA0, sA1, sA2, sB0, sB1, sB2;
    auto SIGLOAD = [&](const Gen& gg, f16x8& o0, f16x8& o1, f16x8& o2) {
        o0 = *(const f16x8*)(sig16 + gg.i0 * CIN + cq * 8);
        o1 = *(const f16x8*)(sig16 + gg.i1 * CIN + cq * 8);
        o2 = *(const f16x8*)(sig16 + gg.i2 * CIN + cq * 8);
    };

    // prologue: gens for chunks 0,1; signal slices for chunk 0
    Gen g0 = LOADGEN(0);
    Gen g1 = LOADGEN(1);
    SIGLOAD(g0, sA0, sA1, sA2);

    int jj = 0, ii = 0;
    for (int it = 0; it < NCHUNK5; ++it) {
        // (1) issue bary loads for it+2 and signal loads for it+1 (both legs
        //     of the dependent idx->gather chain get a full chunk in flight)
        Gen g2 = LOADGEN(it + 2);
        SIGLOAD(g1, sB0, sB1, sB2);

        // (2) phase1: x for chunk it from REGISTERS (no memory wait), one ds_write
        {
            f16x8 hv;
            #pragma unroll
            for (int e = 0; e < 8; ++e) {
                float xf = g0.w0 * (float)sA0[e]
                         + g0.w1 * (float)sA1[e]
                         + g0.w2 * (float)sA2[e];
                hv[e] = (_Float16)xf;
            }
            *(f16x8*)&Axs[vt * 72 + cq * 8] = hv;
        }
        __syncthreads();   // bar1: Axs ready

        // (3) phase2: B from L2, A from LDS, 32 MFMA
        const int m = (jj + wn) & 7;
        #pragma unroll
        for (int kk = 0; kk < 2; ++kk) {
            f16x8 bfrag[4];
            #pragma unroll
            for (int nf = 0; nf < 4; ++nf) {
                const int col = m * 64 + nf * 16 + l15;
                bfrag[nf] = *(const f16x8*)(bk + ((ii * 512 + col) << 6) + kk * 32 + g * 8);
            }
            f16x8 afrag[4];
            #pragma unroll
            for (int mf = 0; mf < 4; ++mf)
                afrag[mf] = *(const f16x8*)&Axs[(mf * 16 + l15) * 72 + (kk * 4 + g) * 8];

            #pragma unroll
            for (int nf = 0; nf < 4; ++nf)
                #pragma unroll
                for (int mf = 0; mf < 4; ++mf)
                    acc[mf][nf] = __builtin_amdgcn_mfma_f32_16x16x32_f16(
                        afrag[mf], bfrag[nf], acc[mf][nf], 0, 0, 0);
        }
        __syncthreads();   // bar2: Axs free for next chunk's phase1

        // (4) rotate pipeline
        g0 = g1; g1 = g2;
        sA0 = sB0; sA1 = sB1; sA2 = sB2;
        if (++ii == NR) { ii = 0; ++jj; }
    }

    // ---- epilogue: wave wn owns rotation wn; norms per row ----
    #pragma unroll
    for (int mf = 0; mf < 4; ++mf)
        #pragma unroll
        for (int ri = 0; ri < 4; ++ri) {
            float s = 0.f;
            #pragma unroll
            for (int nf = 0; nf < 4; ++nf) {
                float vv = acc[mf][nf][ri];
                s = fmaf(vv, vv, s);
            }
            #pragma unroll
            for (int off = 1; off < 16; off <<= 1)
                s += __shfl_xor(s, off);
            if (l15 == 0) nrm[mf * 16 + g * 4 + ri][wn] = s;
        }
    __syncthreads();

    if (tid < BM2) {
        const int v = vbase + tid;
        float bn = nrm[tid][0];
        float sec = -1e30f;
        int best = 0;
        #pragma unroll
        for (int k = 1; k < NT; ++k) {
            float nv = nrm[tid][k];
            if (nv > bn)       { sec = bn; bn = nv; best = k; }
            else if (nv > sec) { sec = nv; }
        }
        // fp16-input (double-rounded x) norm^2 error ~1.2e-2 sigma; ~6 sigma
        const bool flag = (bn - sec) <= (7e-2f + 2e-3f * bn);
        besti[tid] = flag ? -1 : best;
        if (flag && v < NV) { int p = atomicAdd(wl, 1); wl[1 + p] = v; }
    }
    __syncthreads();

    #pragma unroll
    for (int mf = 0; mf < 4; ++mf)
        #pragma unroll
        for (int ri = 0; ri < 4; ++ri) {
            const int row = mf * 16 + g * 4 + ri;
            const int v   = vbase + row;
            const int bsel = (v < NV) ? besti[row] : -1;
            if (bsel == wn) {
                #pragma unroll
                for (int nf = 0; nf < 4; ++nf) {
                    const int d = nf * 16 + l15;
                    out[v * COUT + d] = fmaxf(acc[mf][nf][ri], 0.0f);
                }
            }
        }
}

// ---------- v5 fallback (round-9 proven): gathers from fp32 signal ----------
__global__ __launch_bounds__(512, 4) void geo_mfma5(
    const float* __restrict__ signal,
    const float* __restrict__ bary_w,
    const int*   __restrict__ bary_idx,
    const _Float16* __restrict__ bk,
    float* __restrict__ out,
    int*   __restrict__ wl)
{
    __shared__ __align__(16) _Float16 Axs[2][8][BM2][8];
    __shared__ float nrm[BM2][NT];
    __shared__ int   besti[BM2];

    const int tid  = threadIdx.x;
    const int lane = tid & 63;
    const int wn   = tid >> 6;
    const int g    = lane >> 4;
    const int l15  = lane & 15;
    const int vbase = blockIdx.x * BM2;

    const int vt = (tid >> 6) * 8 + (lane & 7);
    const int cq = lane >> 3;
    const int v_mine = vbase + vt;
    const bool v_ok = (v_mine < NV);

    f32x4 acc[4][4];
    {
        f32x4 z = {0.f, 0.f, 0.f, 0.f};
        #pragma unroll
        for (int mf = 0; mf < 4; ++mf)
            #pragma unroll
            for (int nf = 0; nf < 4; ++nf) acc[mf][nf] = z;
    }

    float bw0, bw1, bw2;
    int   bi0, bi1, bi2;

    auto SLOADB = [&](int it2) {
        const int j2 = it2 / NR;
        const int i2 = it2 - j2 * NR;
        if (v_ok) {
            const int base = v_mine * BARY + (i2 * NT + j2) * 3;
            bw0 = bary_w[base + 0];
            bw1 = bary_w[base + 1];
            bw2 = bary_w[base + 2];
            bi0 = bary_idx[base + 0];
            bi1 = bary_idx[base + 1];
            bi2 = bary_idx[base + 2];
        }
    };
    auto SWRITE = [&](int b) {
        float xv[8];
        if (v_ok) {
            const int ch = cq * 8;
            const float4* s0 = (const float4*)(signal + bi0 * CIN + ch);
            const float4* s1 = (const float4*)(signal + bi1 * CIN + ch);
            const float4* s2 = (const float4*)(signal + bi2 * CIN + ch);
            const float4 p0 = s0[0], p1 = s0[1];
            const float4 q0 = s1[0], q1 = s1[1];
            const float4 r0 = s2[0], r1 = s2[1];
            xv[0] = bw0*p0.x + bw1*q0.x + bw2*r0.x;
            xv[1] = bw0*p0.y + bw1*q0.y + bw2*r0.y;
            xv[2] = bw0*p0.z + bw1*q0.z + bw2*r0.z;
            xv[3] = bw0*p0.w + bw1*q0.w + bw2*r0.w;
            xv[4] = bw0*p1.x + bw1*q1.x + bw2*r1.x;
            xv[5] = bw0*p1.y + bw1*q1.y + bw2*r1.y;
            xv[6] = bw0*p1.z + bw1*q1.z + bw2*r1.z;
            xv[7] = bw0*p1.w + bw1*q1.w + bw2*r1.w;
        } else {
            #pragma unroll
            for (int e = 0; e < 8; ++e) xv[e] = 0.f;
        }
        f16x8 hv;
        #pragma unroll
        for (int e = 0; e < 8; ++e) hv[e] = (_Float16)xv[e];
        *(f16x8*)&Axs[b][cq][vt][0] = hv;
    };

    SLOADB(0);
    SWRITE(0);
    SLOADB(1);
    __syncthreads();

    for (int it = 0; it < NCHUNK5; ++it) {
        const int b = it & 1;
        const int j = it / NR;
        const int i = it - j * NR;
        const int m = (j + wn) & 7;

        #pragma unroll
        for (int kk = 0; kk < 2; ++kk) {
            f16x8 bfrag[4];
            #pragma unroll
            for (int nf = 0; nf < 4; ++nf) {
                const int col = m * 64 + nf * 16 + l15;
                bfrag[nf] = *(const f16x8*)(bk + ((i * 512 + col) << 6) + kk * 32 + g * 8);
            }
            f16x8 afrag[4];
            #pragma unroll
            for (int mf = 0; mf < 4; ++mf)
                afrag[mf] = *(const f16x8*)&Axs[b][kk * 4 + g][mf * 16 + l15][0];

            #pragma unroll
            for (int nf = 0; nf < 4; ++nf)
                #pragma unroll
                for (int mf = 0; mf < 4; ++mf)
                    acc[mf][nf] = __builtin_amdgcn_mfma_f32_16x16x32_f16(
                        afrag[mf], bfrag[nf], acc[mf][nf], 0, 0, 0);
        }

        if (it + 1 < NCHUNK5) {
            SWRITE(b ^ 1);
            if (it + 2 < NCHUNK5) SLOADB(it + 2);
        }
        __syncthreads();
    }

    #pragma unroll
    for (int mf = 0; mf < 4; ++mf)
        #pragma unroll
        for (int ri = 0; ri < 4; ++ri) {
            float s = 0.f;
            #pragma unroll
            for (int nf = 0; nf < 4; ++nf) {
                float vv = acc[mf][nf][ri];
                s = fmaf(vv, vv, s);
            }
            #pragma unroll
            for (int off = 1; off < 16; off <<= 1)
                s += __shfl_xor(s, off);
            if (l15 == 0) nrm[mf * 16 + g * 4 + ri][wn] = s;
        }
    __syncthreads();

    if (tid < BM2) {
        const int v = vbase + tid;
        float bn = nrm[tid][0];
        float sec = -1e30f;
        int best = 0;
        #pragma unroll
        for (int k = 1; k < NT; ++k) {
            float nv = nrm[tid][k];
            if (nv > bn)       { sec = bn; bn = nv; best = k; }
            else if (nv > sec) { sec = nv; }
        }
        const bool flag = (bn - sec) <= (5.5e-2f + 1.5e-3f * bn);
        besti[tid] = flag ? -1 : best;
        if (flag && v < NV) { int p = atomicAdd(wl, 1); wl[1 + p] = v; }
    }
    __syncthreads();

    #pragma unroll
    for (int mf = 0; mf < 4; ++mf)
        #pragma unroll
        for (int ri = 0; ri < 4; ++ri) {
            const int row = mf * 16 + g * 4 + ri;
            const int v   = vbase + row;
            const int bsel = (v < NV) ? besti[row] : -1;
            if (bsel == wn) {
                #pragma unroll
                for (int nf = 0; nf < 4; ++nf) {
                    const int d = nf * 16 + l15;
                    out[v * COUT + d] = fmaxf(acc[mf][nf][ri], 0.0f);
                }
            }
        }
}

// ---------- parallel fp64 refine: one BLOCK (4 waves) per vertex ----------
__global__ __launch_bounds__(256) void geo_refine_f64p(
    const float* __restrict__ signal,
    const float* __restrict__ bary_w,
    const int*   __restrict__ bary_idx,
    const float* __restrict__ kern,
    float*       __restrict__ out,
    const int*   __restrict__ wl,
    int nall)
{
    __shared__ __align__(16) float xs[NR][CIN][NT];
    __shared__ double part[4][NT][COUT];
    __shared__ double convl[NT][COUT];
    __shared__ double nks[NT];
    __shared__ int bestS;

    const int tid  = threadIdx.x;
    const int wave = tid >> 6;
    const int lane = tid & 63;
    const int count = wl ? wl[0] : nall;

    for (int w = blockIdx.x; w < count; w += gridDim.x) {
        const int v = wl ? wl[1 + w] : w;

        for (int ij = wave; ij < NR * NT; ij += 4) {
            const int i = ij >> 3, j = ij & 7;
            const int base = v * BARY + ij * 3;
            const float w0 = bary_w[base], w1 = bary_w[base+1], w2 = bary_w[base+2];
            const int   i0 = bary_idx[base], i1 = bary_idx[base+1], i2 = bary_idx[base+2];
            xs[i][lane][j] = w0 * signal[i0*CIN + lane]
                           + w1 * signal[i1*CIN + lane]
                           + w2 * signal[i2*CIN + lane];
        }
        __syncthreads();

        double acc[NT];
        #pragma unroll
        for (int k = 0; k < NT; ++k) acc[k] = 0.0;

        for (int r = wave * 80; r < wave * 80 + 80; ++r) {
            const int i = r >> 6, c = r & 63;
            const float4 xa = *reinterpret_cast<const float4*>(&xs[i][c][0]);
            const float4 xb = *reinterpret_cast<const float4*>(&xs[i][c][4]);
            const double x8[NT] = {(double)xa.x, (double)xa.y, (double)xa.z, (double)xa.w,
                                   (double)xb.x, (double)xb.y, (double)xb.z, (double)xb.w};
            #pragma unroll
            for (int mm = 0; mm < NT; ++mm) {
                const double kv = (double)kern[((i * NT + mm) * CIN + c) * COUT + lane];
                #pragma unroll
                for (int k = 0; k < NT; ++k)
                    acc[k] = fma(x8[(mm - k + NT) & (NT - 1)], kv, acc[k]);
            }
        }
        #pragma unroll
        for (int k = 0; k < NT; ++k) part[wave][k][lane] = acc[k];
        __syncthreads();

        for (int kd = tid; kd < NT * COUT; kd += 256) {
            const int k = kd >> 6, d = kd & 63;
            convl[k][d] = ((part[0][k][d] + part[1][k][d])
                         + (part[2][k][d] + part[3][k][d]));
        }
        __syncthreads();

        for (int k = wave; k < NT; k += 4) {
            double n = convl[k][lane] * convl[k][lane];
            #pragma unroll
            for (int off = 32; off >= 1; off >>= 1) n += __shfl_xor(n, off);
            if (lane == 0) nks[k] = n;
        }
        __syncthreads();

        if (tid == 0) {
            int best = 0; double bn = nks[0];
            #pragma unroll
            for (int k = 1; k < NT; ++k)
                if (nks[k] > bn) { bn = nks[k]; best = k; }
            bestS = best;
        }
        __syncthreads();

        if (tid < COUT) out[v * COUT + tid] = fmaxf((float)convl[bestS][tid], 0.0f);
        __syncthreads();
    }
}

extern "C" void kernel_launch(void* const* d_in, const int* in_sizes, int n_in,
                              void* d_out, int out_size, void* d_ws, size_t ws_size,
                              hipStream_t stream) {
    const float* signal   = (const float*)d_in[0];
    const float* bary_w   = (const float*)d_in[1];
    const int*   bary_idx = (const int*)d_in[2];
    const float* kern     = (const float*)d_in[3];
    float* out = (float*)d_out;

    if (ws_size >= (size_t)WS_NEED6) {
        int* wl = (int*)d_ws;
        _Float16* bk    = (_Float16*)((char*)d_ws + WL_BYTES);
        _Float16* sig16 = (_Float16*)((char*)d_ws + WL_BYTES + 2u * BK_ELEMS);
        hipMemsetAsync(wl, 0, sizeof(int), stream);
        build_bk5<<<dim3(BK_ELEMS / 256), dim3(256), 0, stream>>>(kern, bk);
        build_sig16<<<dim3(NV * CIN / 256), dim3(256), 0, stream>>>(signal, sig16);
        geo_mfma6<<<dim3(NBLK2), dim3(512), 0, stream>>>(
            bary_w, bary_idx, sig16, bk, out, wl);
        geo_refine_f64p<<<dim3(1024), dim3(256), 0, stream>>>(
            signal, bary_w, bary_idx, kern, out, wl, 0);
    } else if (ws_size >= (size_t)WS_NEED5) {
        int* wl = (int*)d_ws;
        _Float16* bk = (_Float16*)((char*)d_ws + WL_BYTES);
        hipMemsetAsync(wl, 0, sizeof(int), stream);
        build_bk5<<<dim3(BK_ELEMS / 256), dim3(256), 0, stream>>>(kern, bk);
        geo_mfma5<<<dim3(NBLK2), dim3(512), 0, stream>>>(
            signal, bary_w, bary_idx, bk, out, wl);
        geo_refine_f64p<<<dim3(1024), dim3(256), 0, stream>>>(
            signal, bary_w, bary_idx, kern, out, wl, 0);
    } else {
        geo_refine_f64p<<<dim3(1024), dim3(256), 0, stream>>>(
            signal, bary_w, bary_idx, kern, out, nullptr, NV);
    }
}

// Round 11
// 437.657 us; speedup vs baseline: 4.3535x; 1.1625x over previous
//
#include <hip/hip_runtime.h>

#define NV   50000
#define NR   5
#define NT   8
#define CIN  64
#define COUT 64
#define BARY (NR*NT*3)      // 120
#define BK_ELEMS (NR*CIN*NT*COUT)   // 163840 fp16 (320 KB) — L2-resident
#define BM2  64
#define NBLK2 ((NV + BM2 - 1) / BM2)   // 782
#define NCH7 80             // chunks: (j 0..7) x (icc 0..9), K=32 each

#define WL_BYTES 262144
#define SIG16_BYTES (NV*CIN*2)                            // 6.4 MB
#define WS_NEED7 (WL_BYTES + 2u*BK_ELEMS + SIG16_BYTES)   // ~7.0 MB

typedef _Float16 f16x8 __attribute__((ext_vector_type(8)));
typedef _Float16 f16x4 __attribute__((ext_vector_type(4)));
typedef float    f32x4 __attribute__((ext_vector_type(4)));

// ---------- K0a: kernel -> fp16 ws, chunked [icc][col=m*64+d][ck] ----------
// chunk icc covers (i = icc>>1, c = (icc&1)*32 + ck). 32 KB per chunk.
__global__ __launch_bounds__(256) void build_bk7(
    const float* __restrict__ kern, _Float16* __restrict__ bk)
{
    int e   = blockIdx.x * 256 + threadIdx.x;   // icc*16384 + col*32 + ck
    int ck  = e & 31;
    int col = (e >> 5) & 511;
    int icc = e >> 14;
    int i   = icc >> 1;
    int c   = (icc & 1) * 32 + ck;
    int m   = col >> 6;
    int d   = col & 63;
    bk[e] = (_Float16)kern[((i * NT + m) * CIN + c) * COUT + d];
}

// ---------- K0b: signal -> fp16 ----------
__global__ __launch_bounds__(256) void build_sig16(
    const float* __restrict__ signal, _Float16* __restrict__ sig16)
{
    int e = blockIdx.x * 256 + threadIdx.x;
    sig16[e] = (_Float16)signal[e];
}

// ---------- main v7: B through LDS dbuf (coalesced stage), K=32 chunks ----------
__global__ __launch_bounds__(512, 4) void geo_mfma7(
    const float* __restrict__ bary_w,
    const int*   __restrict__ bary_idx,
    const _Float16* __restrict__ sig16,
    const _Float16* __restrict__ bk,
    float* __restrict__ out,
    int*   __restrict__ wl)
{
    __shared__ __align__(16) _Float16 Blds[2][16384];   // 2 x 32 KB
    __shared__ __align__(16) _Float16 Axs[4][BM2][8];   // 4 KB (K=32, single-buf)
    __shared__ float nrm[BM2][NT];                      // 2 KB
    __shared__ int   besti[BM2];

    const int tid  = threadIdx.x;
    const int lane = tid & 63;
    const int wn   = tid >> 6;         // wave wn owns rotation k=wn
    const int g    = lane >> 4;
    const int l15  = lane & 15;
    const int vbase = blockIdx.x * BM2;

    // A-staging mapping: thread -> (vertex vt, ck-quad cq); 4 channels each
    const int vt = tid >> 3;
    const int cq = tid & 7;
    const int v_mine = vbase + vt;
    const bool v_ok = (v_mine < NV);

    f32x4 acc[4][4];
    {
        f32x4 z = {0.f, 0.f, 0.f, 0.f};
        #pragma unroll
        for (int mf = 0; mf < 4; ++mf)
            #pragma unroll
            for (int nf = 0; nf < 4; ++nf) acc[mf][nf] = z;
    }

    struct Gen { float w0, w1, w2; int i0, i1, i2; };
    auto LOADGEN = [&](int it2) -> Gen {
        Gen gg;
        const int itc = (it2 < NCH7) ? it2 : (NCH7 - 1);
        const int j2   = itc / 10;
        const int icc2 = itc - j2 * 10;
        const int i2   = icc2 >> 1;
        if (v_ok) {
            const int base = v_mine * BARY + (i2 * NT + j2) * 3;
            gg.w0 = bary_w[base + 0];
            gg.w1 = bary_w[base + 1];
            gg.w2 = bary_w[base + 2];
            gg.i0 = bary_idx[base + 0];
            gg.i1 = bary_idx[base + 1];
            gg.i2 = bary_idx[base + 2];
        } else {
            gg.w0 = gg.w1 = gg.w2 = 0.f;
            gg.i0 = gg.i1 = gg.i2 = 0;
        }
        return gg;
    };

    // sig slice for chunk: 4 ch at c = (icc&1)*32 + cq*4
    f16x4 sA0, sA1, sA2, sB0, sB1, sB2;
    auto SIGLOAD = [&](const Gen& gg, int it2, f16x4& o0, f16x4& o1, f16x4& o2) {
        const int itc = (it2 < NCH7) ? it2 : (NCH7 - 1);
        const int icc2 = itc - (itc / 10) * 10;
        const int coff = (icc2 & 1) * 32 + cq * 4;
        o0 = *(const f16x4*)(sig16 + gg.i0 * CIN + coff);
        o1 = *(const f16x4*)(sig16 + gg.i1 * CIN + coff);
        o2 = *(const f16x4*)(sig16 + gg.i2 * CIN + coff);
    };

    // B chunk reg-staging: wave w covers elems w*2048 + r*512 + lane*8, r=0..3
    f16x8 breg0, breg1, breg2, breg3;
    auto BLOADR = [&](int icc2) {
        const _Float16* src = bk + icc2 * 16384 + wn * 2048 + lane * 8;
        breg0 = *(const f16x8*)(src + 0 * 512);
        breg1 = *(const f16x8*)(src + 1 * 512);
        breg2 = *(const f16x8*)(src + 2 * 512);
        breg3 = *(const f16x8*)(src + 3 * 512);
    };
    auto BWRITE = [&](int b) {
        _Float16* dst = &Blds[b][wn * 2048 + lane * 8];
        *(f16x8*)(dst + 0 * 512) = breg0;
        *(f16x8*)(dst + 1 * 512) = breg1;
        *(f16x8*)(dst + 2 * 512) = breg2;
        *(f16x8*)(dst + 3 * 512) = breg3;
    };

    // ---- prologue ----
    Gen g0 = LOADGEN(0);
    Gen g1 = LOADGEN(1);
    SIGLOAD(g0, 0, sA0, sA1, sA2);
    BLOADR(0);
    BWRITE(0);
    __syncthreads();

    int cur = 0;
    for (int it = 0; it < NCH7; ++it) {
        const int j   = it / 10;
        const int icc = it - j * 10;
        const int m   = (j + wn) & 7;

        // ---- phase1: x(it) from regs -> Axs; issue next sig/bary ----
        {
            f16x4 hv;
            #pragma unroll
            for (int e = 0; e < 4; ++e) {
                float xf = g0.w0 * (float)sA0[e]
                         + g0.w1 * (float)sA1[e]
                         + g0.w2 * (float)sA2[e];
                hv[e] = (_Float16)xf;
            }
            *(f16x4*)&Axs[cq >> 1][vt][(cq & 1) * 4] = hv;
        }
        SIGLOAD(g1, it + 1, sB0, sB1, sB2);
        Gen g2 = LOADGEN(it + 2);
        __syncthreads();   // bar1: Axs ready (drains stage loads too)

        // ---- phase2: issue B(it+1) loads early; MFMA from LDS; write B ----
        const int iccn = (it + 1 < NCH7) ? ((it + 1) - ((it + 1) / 10) * 10) : 0;
        if (it + 1 < NCH7) BLOADR(iccn);

        f16x8 afrag[4];
        #pragma unroll
        for (int mf = 0; mf < 4; ++mf)
            afrag[mf] = *(const f16x8*)&Axs[g][mf * 16 + l15][0];

        #pragma unroll
        for (int nf = 0; nf < 4; ++nf) {
            const int col = m * 64 + nf * 16 + l15;
            const f16x8 bfrag = *(const f16x8*)&Blds[cur][col * 32 + g * 8];
            #pragma unroll
            for (int mf = 0; mf < 4; ++mf)
                acc[mf][nf] = __builtin_amdgcn_mfma_f32_16x16x32_f16(
                    afrag[mf], bfrag, acc[mf][nf], 0, 0, 0);
        }

        if (it + 1 < NCH7) BWRITE(cur ^ 1);   // waits vmcnt on breg*
        __syncthreads();   // bar2: B(it+1) visible; Axs free

        // rotate pipeline
        g0 = g1; g1 = g2;
        sA0 = sB0; sA1 = sB1; sA2 = sB2;
        cur ^= 1;
    }

    // ---- epilogue: wave wn owns rotation wn; norms per row ----
    #pragma unroll
    for (int mf = 0; mf < 4; ++mf)
        #pragma unroll
        for (int ri = 0; ri < 4; ++ri) {
            float s = 0.f;
            #pragma unroll
            for (int nf = 0; nf < 4; ++nf) {
                float vv = acc[mf][nf][ri];
                s = fmaf(vv, vv, s);
            }
            #pragma unroll
            for (int off = 1; off < 16; off <<= 1)
                s += __shfl_xor(s, off);
            if (l15 == 0) nrm[mf * 16 + g * 4 + ri][wn] = s;
        }
    __syncthreads();

    if (tid < BM2) {
        const int v = vbase + tid;
        float bn = nrm[tid][0];
        float sec = -1e30f;
        int best = 0;
        #pragma unroll
        for (int k = 1; k < NT; ++k) {
            float nv = nrm[tid][k];
            if (nv > bn)       { sec = bn; bn = nv; best = k; }
            else if (nv > sec) { sec = nv; }
        }
        // fp16-input norm^2 error ~1.2e-2 sigma; ~6 sigma + rel term
        const bool flag = (bn - sec) <= (7e-2f + 2e-3f * bn);
        besti[tid] = flag ? -1 : best;
        if (flag && v < NV) { int p = atomicAdd(wl, 1); wl[1 + p] = v; }
    }
    __syncthreads();

    #pragma unroll
    for (int mf = 0; mf < 4; ++mf)
        #pragma unroll
        for (int ri = 0; ri < 4; ++ri) {
            const int row = mf * 16 + g * 4 + ri;
            const int v   = vbase + row;
            const int bsel = (v < NV) ? besti[row] : -1;
            if (bsel == wn) {
                #pragma unroll
                for (int nf = 0; nf < 4; ++nf) {
                    const int d = nf * 16 + l15;
                    out[v * COUT + d] = fmaxf(acc[mf][nf][ri], 0.0f);
                }
            }
        }
}

// ---------- parallel fp64 refine: one BLOCK (4 waves) per vertex ----------
__global__ __launch_bounds__(256) void geo_refine_f64p(
    const float* __restrict__ signal,
    const float* __restrict__ bary_w,
    const int*   __restrict__ bary_idx,
    const float* __restrict__ kern,
    float*       __restrict__ out,
    const int*   __restrict__ wl,
    int nall)
{
    __shared__ __align__(16) float xs[NR][CIN][NT];
    __shared__ double part[4][NT][COUT];
    __shared__ double convl[NT][COUT];
    __shared__ double nks[NT];
    __shared__ int bestS;

    const int tid  = threadIdx.x;
    const int wave = tid >> 6;
    const int lane = tid & 63;
    const int count = wl ? wl[0] : nall;

    for (int w = blockIdx.x; w < count; w += gridDim.x) {
        const int v = wl ? wl[1 + w] : w;

        for (int ij = wave; ij < NR * NT; ij += 4) {
            const int i = ij >> 3, j = ij & 7;
            const int base = v * BARY + ij * 3;
            const float w0 = bary_w[base], w1 = bary_w[base+1], w2 = bary_w[base+2];
            const int   i0 = bary_idx[base], i1 = bary_idx[base+1], i2 = bary_idx[base+2];
            xs[i][lane][j] = w0 * signal[i0*CIN + lane]
                           + w1 * signal[i1*CIN + lane]
                           + w2 * signal[i2*CIN + lane];
        }
        __syncthreads();

        double acc[NT];
        #pragma unroll
        for (int k = 0; k < NT; ++k) acc[k] = 0.0;

        for (int r = wave * 80; r < wave * 80 + 80; ++r) {
            const int i = r >> 6, c = r & 63;
            const float4 xa = *reinterpret_cast<const float4*>(&xs[i][c][0]);
            const float4 xb = *reinterpret_cast<const float4*>(&xs[i][c][4]);
            const double x8[NT] = {(double)xa.x, (double)xa.y, (double)xa.z, (double)xa.w,
                                   (double)xb.x, (double)xb.y, (double)xb.z, (double)xb.w};
            #pragma unroll
            for (int mm = 0; mm < NT; ++mm) {
                const double kv = (double)kern[((i * NT + mm) * CIN + c) * COUT + lane];
                #pragma unroll
                for (int k = 0; k < NT; ++k)
                    acc[k] = fma(x8[(mm - k + NT) & (NT - 1)], kv, acc[k]);
            }
        }
        #pragma unroll
        for (int k = 0; k < NT; ++k) part[wave][k][lane] = acc[k];
        __syncthreads();

        for (int kd = tid; kd < NT * COUT; kd += 256) {
            const int k = kd >> 6, d = kd & 63;
            convl[k][d] = ((part[0][k][d] + part[1][k][d])
                         + (part[2][k][d] + part[3][k][d]));
        }
        __syncthreads();

        for (int k = wave; k < NT; k += 4) {
            double n = convl[k][lane] * convl[k][lane];
            #pragma unroll
            for (int off = 32; off >= 1; off >>= 1) n += __shfl_xor(n, off);
            if (lane == 0) nks[k] = n;
        }
        __syncthreads();

        if (tid == 0) {
            int best = 0; double bn = nks[0];
            #pragma unroll
            for (int k = 1; k < NT; ++k)
                if (nks[k] > bn) { bn = nks[k]; best = k; }
            bestS = best;
        }
        __syncthreads();

        if (tid < COUT) out[v * COUT + tid] = fmaxf((float)convl[bestS][tid], 0.0f);
        __syncthreads();
    }
}

extern "C" void kernel_launch(void* const* d_in, const int* in_sizes, int n_in,
                              void* d_out, int out_size, void* d_ws, size_t ws_size,
                              hipStream_t stream) {
    const float* signal   = (const float*)d_in[0];
    const float* bary_w   = (const float*)d_in[1];
    const int*   bary_idx = (const int*)d_in[2];
    const float* kern     = (const float*)d_in[3];
    float* out = (float*)d_out;

    if (ws_size >= (size_t)WS_NEED7) {
        int* wl = (int*)d_ws;
        _Float16* bk    = (_Float16*)((char*)d_ws + WL_BYTES);
        _Float16* sig16 = (_Float16*)((char*)d_ws + WL_BYTES + 2u * BK_ELEMS);
        hipMemsetAsync(wl, 0, sizeof(int), stream);
        build_bk7<<<dim3(BK_ELEMS / 256), dim3(256), 0, stream>>>(kern, bk);
        build_sig16<<<dim3(NV * CIN / 256), dim3(256), 0, stream>>>(signal, sig16);
        geo_mfma7<<<dim3(NBLK2), dim3(512), 0, stream>>>(
            bary_w, bary_idx, sig16, bk, out, wl);
        geo_refine_f64p<<<dim3(1024), dim3(256), 0, stream>>>(
            signal, bary_w, bary_idx, kern, out, wl, 0);
    } else {
        geo_refine_f64p<<<dim3(1024), dim3(256), 0, stream>>>(
            signal, bary_w, bary_idx, kern, out, nullptr, NV);
    }
}